// Round 8
// baseline (2722.906 us; speedup 1.0000x reference)
//
#include <hip/hip_runtime.h>
#include <math.h>

#define B_SZ   64
#define TX_SZ  200
#define TY_SZ  100
#define D_MODEL 512
#define H_SZ   8
#define DK_SZ  64
#define DFF_SZ 2048
#define L_SZ   4
#define V_SZ   30

#define NEG_BIG -1.0e30f

// attention P-scratch: f32 scores, per-wave region [16 rows][PSTRF cols].
// PSTRF=204: 4 waves x 16 x 204 x 4B = 52224 B -> 3 blocks/CU.
#define PSTRF 204
#define ATT_LDSF (4 * 16 * PSTRF)

typedef unsigned short u16;
typedef __attribute__((ext_vector_type(8))) short short8;
typedef __attribute__((ext_vector_type(4))) short short4t;
typedef __attribute__((ext_vector_type(4))) float f32x4;
typedef __attribute__((ext_vector_type(4))) unsigned short u16x4;

__device__ __forceinline__ float b2f(u16 h) {
    union { unsigned int u; float f; } v; v.u = ((unsigned int)h) << 16; return v.f;
}
__device__ __forceinline__ u16 f2b(float f) {
    union { float f; unsigned int u; } v; v.f = f;
    unsigned int r = v.u + 0x7fffu + ((v.u >> 16) & 1u);
    return (u16)(r >> 16);
}

#define GLD16(gp, lp) __builtin_amdgcn_global_load_lds( \
    (const __attribute__((address_space(1))) unsigned int*)(gp), \
    (__attribute__((address_space(3))) unsigned int*)(lp), 16, 0, 0)

// ---------------- cast f32 -> bf16, 4 elems/thread ----------------
__global__ __launch_bounds__(256)
void castw_kernel(const float* __restrict__ in, u16* __restrict__ out, int n4) {
    int i = blockIdx.x * 256 + threadIdx.x;
    if (i < n4) {
        f32x4 v = ((const f32x4*)in)[i];
        u16x4 o;
        o.x = f2b(v.x); o.y = f2b(v.y); o.z = f2b(v.z); o.w = f2b(v.w);
        ((u16x4*)out)[i] = o;
    }
}

// ---------------- bit-pack mask rows: [rows][S] int32 -> [rows][wpr] u32 ------
// bit = 1 iff mask == 1 (i.e. position is masked out). Wave per row, ballot.
__global__ __launch_bounds__(256)
void maskpack_kernel(const int* __restrict__ mask, unsigned* __restrict__ bits,
                     int rows, int S, int wpr) {
    int row = blockIdx.x * 4 + (threadIdx.x >> 6);
    int lane = threadIdx.x & 63;
    if (row >= rows) return;
    const int* mr = mask + (size_t)row * S;
    unsigned* br = bits + (size_t)row * wpr;
    for (int s0 = 0; s0 < S; s0 += 64) {
        int s = s0 + lane;
        int v = (s < S) ? mr[s] : 0;
        unsigned long long bm = __ballot(v == 1);
        if (lane == 0) {
            br[s0 >> 5] = (unsigned)bm;
            if ((s0 >> 5) + 1 < wpr) br[(s0 >> 5) + 1] = (unsigned)(bm >> 32);
        }
    }
}

// ---------------- transpose V slice -> Vt[(b*8+h)*64 + d][spad] ---------------
__global__ __launch_bounds__(256)
void vtrans_kernel(const u16* __restrict__ V, int ldv, u16* __restrict__ Vt,
                   int S, int spad) {
    __shared__ u16 t[16][72];
    const int bh = blockIdx.x;
    const int s0 = blockIdx.y * 16;
    const int h = bh & 7, b = bh >> 3;
    const int tid = threadIdx.x;
    {
        int sl = tid >> 4, c4 = (tid & 15) * 4;
        int s = s0 + sl;
        int ss = (s < S) ? s : S - 1;
        u16x4 v = *(const u16x4*)(V + (size_t)(b * S + ss) * ldv + h * 64 + c4);
        *(u16x4*)&t[sl][c4] = v;
    }
    __syncthreads();
    int d = tid >> 2, j0 = (tid & 3) * 4;
    if (s0 + j0 < spad) {
        u16x4 o;
        o.x = (s0 + j0 + 0 < S) ? t[j0 + 0][d] : (u16)0;
        o.y = (s0 + j0 + 1 < S) ? t[j0 + 1][d] : (u16)0;
        o.z = (s0 + j0 + 2 < S) ? t[j0 + 2][d] : (u16)0;
        o.w = (s0 + j0 + 3 < S) ? t[j0 + 3][d] : (u16)0;
        *(u16x4*)(Vt + ((size_t)bh * 64 + d) * spad + s0 + j0) = o;
    }
}

// ---------------- LayerNorm (rows x 512): wave per row, no barriers ----------
__global__ __launch_bounds__(256)
void ln_kernel(const float* __restrict__ in, const float* __restrict__ g,
               const float* __restrict__ b, float* outf, u16* outb, int rows) {
    int row = blockIdx.x * 4 + (threadIdx.x >> 6);
    int lane = threadIdx.x & 63;
    if (row >= rows) return;
    const f32x4* xr = (const f32x4*)(in + (size_t)row * D_MODEL);
    f32x4 v0 = xr[lane];
    f32x4 v1 = xr[lane + 64];
    float s  = v0.x + v0.y + v0.z + v0.w + v1.x + v1.y + v1.z + v1.w;
    float ss = v0.x*v0.x + v0.y*v0.y + v0.z*v0.z + v0.w*v0.w
             + v1.x*v1.x + v1.y*v1.y + v1.z*v1.z + v1.w*v1.w;
    #pragma unroll
    for (int off = 1; off < 64; off <<= 1) {
        s  += __shfl_xor(s, off, 64);
        ss += __shfl_xor(ss, off, 64);
    }
    float mean = s * (1.0f / D_MODEL);
    float var  = ss * (1.0f / D_MODEL) - mean * mean;
    float rstd = rsqrtf(var + 1e-5f);
    f32x4 g0 = ((const f32x4*)g)[lane],      g1 = ((const f32x4*)g)[lane + 64];
    f32x4 b0 = ((const f32x4*)b)[lane],      b1 = ((const f32x4*)b)[lane + 64];
    f32x4 o0, o1;
    o0.x = (v0.x - mean) * rstd * g0.x + b0.x;
    o0.y = (v0.y - mean) * rstd * g0.y + b0.y;
    o0.z = (v0.z - mean) * rstd * g0.z + b0.z;
    o0.w = (v0.w - mean) * rstd * g0.w + b0.w;
    o1.x = (v1.x - mean) * rstd * g1.x + b1.x;
    o1.y = (v1.y - mean) * rstd * g1.y + b1.y;
    o1.z = (v1.z - mean) * rstd * g1.z + b1.z;
    o1.w = (v1.w - mean) * rstd * g1.w + b1.w;
    if (outf) {
        f32x4* of = (f32x4*)(outf + (size_t)row * D_MODEL);
        of[lane] = o0; of[lane + 64] = o1;
    }
    if (outb) {
        u16x4* ob = (u16x4*)(outb + (size_t)row * D_MODEL);
        u16x4 p0, p1;
        p0.x = f2b(o0.x); p0.y = f2b(o0.y); p0.z = f2b(o0.z); p0.w = f2b(o0.w);
        p1.x = f2b(o1.x); p1.y = f2b(o1.y); p1.z = f2b(o1.z); p1.w = f2b(o1.w);
        ob[lane] = p0; ob[lane + 64] = p1;
    }
}

// ---------------- MFMA GEMM v3: counted-vmcnt pipelined K-loop ----------------
// Double-buffered LDS; stage tile t+1, then wait ONLY for tile t's loads
// (s_waitcnt vmcnt(LPS), never 0 in-loop) + raw s_barrier. The prefetch for
// t+1 stays in flight across the barrier (T3/T4 recipe). Second barrier (no
// drain) protects buf before overwrite. sched_barrier(0) pins ordering.
template<int BN>
__global__ __launch_bounds__(256)
void gemm_mfma_t(const u16* __restrict__ A, int lda,
                 const u16* __restrict__ W, int ldw,
                 float* outf, int ldcf, u16* outb, int ldcb,
                 const float* __restrict__ bias,
                 const float* __restrict__ resid, int ldr,
                 int relu, int K, int NP, int q8) {
    constexpr int NJ = BN / 32;
    __shared__ u16 Alds[2][128 * 32];
    __shared__ u16 Blds[2][BN * 32];
    const int tid  = threadIdx.x;
    const int wave = tid >> 6, lane = tid & 63;
    const int lr = lane & 15, lq = lane >> 4;
    const int wm = (wave >> 1) * 64, wn = (wave & 1) * (BN / 2);
    const int bid = blockIdx.x;
    const int sid = q8 ? ((bid & 7) * q8 + (bid >> 3)) : bid;
    const int m0 = (sid / NP) * 128, n0 = (sid % NP) * BN;
    const int grow = tid >> 2;
    const int gcol = (tid & 3) * 8;
    const int woff = wave * 512;

    f32x4 zero = {0.f, 0.f, 0.f, 0.f};
    f32x4 acc[4][NJ];
    #pragma unroll
    for (int i = 0; i < 4; ++i)
        #pragma unroll
        for (int j = 0; j < NJ; ++j) acc[i][j] = zero;

    const u16* Ag = A + (size_t)m0 * lda;
    const u16* Wg = W + (size_t)n0 * ldw;

    auto stage = [&](int buf, int k0) {
        GLD16(Ag + (size_t)grow * lda + k0 + gcol,        &Alds[buf][woff]);
        GLD16(Ag + (size_t)(64 + grow) * lda + k0 + gcol, &Alds[buf][2048 + woff]);
        GLD16(Wg + (size_t)grow * ldw + k0 + gcol,        &Blds[buf][woff]);
        if (BN == 128)
            GLD16(Wg + (size_t)(64 + grow) * ldw + k0 + gcol, &Blds[buf][2048 + woff]);
    };

    stage(0, 0);                       // loads for tile 0 in flight
    const int nt = K >> 5;
    int cur = 0;
    for (int t = 0; t < nt; ++t) {
        if (t + 1 < nt) {
            stage(cur ^ 1, (t + 1) << 5);          // issue next tile's loads
            // wait for tile t's loads only; keep the LPS newest in flight
            if constexpr (BN == 128)
                asm volatile("s_waitcnt vmcnt(4)" ::: "memory");
            else
                asm volatile("s_waitcnt vmcnt(3)" ::: "memory");
        } else {
            asm volatile("s_waitcnt vmcnt(0)" ::: "memory");
        }
        __builtin_amdgcn_s_barrier();              // all waves: buf[cur] ready
        __builtin_amdgcn_sched_barrier(0);
        short8 af[4], bfr[NJ];
        #pragma unroll
        for (int i = 0; i < 4; ++i)
            af[i] = *(const short8*)&Alds[cur][(wm + i * 16 + lr) * 32 + lq * 8];
        #pragma unroll
        for (int j = 0; j < NJ; ++j)
            bfr[j] = *(const short8*)&Blds[cur][(wn + j * 16 + lr) * 32 + lq * 8];
        #pragma unroll
        for (int i = 0; i < 4; ++i)
            #pragma unroll
            for (int j = 0; j < NJ; ++j)
                acc[i][j] = __builtin_amdgcn_mfma_f32_16x16x32_bf16(af[i], bfr[j], acc[i][j], 0, 0, 0);
        __builtin_amdgcn_s_barrier();              // readers done before overwrite
        __builtin_amdgcn_sched_barrier(0);
        cur ^= 1;
    }

    #pragma unroll
    for (int i = 0; i < 4; ++i) {
        #pragma unroll
        for (int r = 0; r < 4; ++r) {
            int m = m0 + wm + i * 16 + lq * 4 + r;
            #pragma unroll
            for (int j = 0; j < NJ; ++j) {
                int n = n0 + wn + j * 16 + lr;
                float c = acc[i][j][r];
                if (bias)  c += bias[n];
                if (resid) c += resid[(size_t)m * ldr + n];
                if (relu)  c = fmaxf(c, 0.f);
                if (outf) outf[(size_t)m * ldcf + n] = c;
                if (outb) outb[(size_t)m * ldcb + n] = f2b(c);
            }
        }
    }
}

// ---------------- attention v10: batched-prefetch flash -----------------------
// Grid (B*H, T-tiles), 4 waves/block, one 16-row t-tile per wave, no barriers.
// All mask words (mrow[4][7]) and all K fragments (kb[13][2]) are prefetched
// BEFORE any MFMA -> one latency round instead of 13 serialized batches.
// Vt fragments (vbr[7][4]) are issued before phase 2 so their latency hides
// under the exp/softmax VALU work. All arrays statically indexed.
// Note: s>>5 == st>>1 (s = st*16+lm, lm<16), so mask word index is static.
__global__ __launch_bounds__(256, 2)
void attn_kernel(u16* __restrict__ Q, int ldq, const u16* __restrict__ K, int ldk,
                 const u16* __restrict__ Vt, int spad,
                 const unsigned* __restrict__ mbits, int mwpr,
                 int T, int S, int causal, float rscale) {
    __shared__ float Pl[ATT_LDSF];
    const int bh = blockIdx.x, tile = blockIdx.y;
    const int h = bh & 7, b = bh >> 3;
    const int tid = threadIdx.x, wave = tid >> 6, lane = tid & 63;
    const int lm = lane & 15, quad = lane >> 4;
    const int t0 = tile * 64 + wave * 16;
    if (t0 >= T) return;

    const u16* Kg = K + (size_t)(b * S) * ldk + h * DK_SZ;
    const u16* Vg = Vt + (size_t)bh * 64 * spad;
    u16* Qg = Q + (size_t)(b * T) * ldq + h * DK_SZ;

    const int stiles = (S + 15) >> 4;
    int stmax = stiles;
    if (causal) { int c = (t0 >> 4) + 1; if (c < stmax) stmax = c; }
    const int Scap8 = (S + 7) & ~7;
    int Pcap = stmax * 16; if (Pcap > Scap8) Pcap = Scap8;

    float* Pw = Pl + wave * (16 * PSTRF);

    // ---- prefetch: Q, all mask words, all K fragments (one latency round) ----
    int qr = t0 + lm; if (qr >= T) qr = T - 1;
    const u16* qrow = Qg + (size_t)qr * ldq;
    short8 qa0 = *(const short8*)(qrow + quad * 8);
    short8 qa1 = *(const short8*)(qrow + 32 + quad * 8);

    unsigned mrow[4][7];
    if (mbits) {
        #pragma unroll
        for (int r = 0; r < 4; ++r) {
            int t = t0 + quad * 4 + r;
            int tc = (t < T) ? t : T - 1;
            const unsigned* mp = mbits + (size_t)(b * T + tc) * mwpr;
            #pragma unroll
            for (int w = 0; w < 7; ++w)
                if (w < mwpr) mrow[r][w] = mp[w];
        }
    }

    short8 kb[13][2];
    #pragma unroll
    for (int st = 0; st < 13; ++st) if (st < stmax) {
        int srow = st * 16 + lm; if (srow >= S) srow = S - 1;
        const u16* kp = Kg + (size_t)srow * ldk + quad * 8;
        kb[st][0] = *(const short8*)kp;
        kb[st][1] = *(const short8*)(kp + 32);
    }

    const short8 zero8 = {0, 0, 0, 0, 0, 0, 0, 0};
    const f32x4 zerof = {0.f, 0.f, 0.f, 0.f};

    // -------- phase 1: QK^T + mask/scale + running max, scores -> LDS f32 -----
    float mx[4] = {NEG_BIG, NEG_BIG, NEG_BIG, NEG_BIG};
    #pragma unroll
    for (int st = 0; st < 13; ++st) if (st < stmax) {
        f32x4 c = zerof;
        c = __builtin_amdgcn_mfma_f32_16x16x32_bf16(qa0, kb[st][0], c, 0, 0, 0);
        c = __builtin_amdgcn_mfma_f32_16x16x32_bf16(qa1, kb[st][1], c, 0, 0, 0);
        int s = st * 16 + lm;
        #pragma unroll
        for (int r = 0; r < 4; ++r) {
            int t = t0 + quad * 4 + r;
            bool valid = (s < S) && (!causal || s <= t);
            if (valid && mbits)
                valid = ((mrow[r][st >> 1] >> (((st & 1) << 4) + lm)) & 1u) == 0;
            float f = valid ? c[r] * rscale : NEG_BIG;
            mx[r] = fmaxf(mx[r], f);
            if (s < PSTRF) Pw[(quad * 4 + r) * PSTRF + s] = f;
        }
    }
    #pragma unroll
    for (int r = 0; r < 4; ++r) {
        #pragma unroll
        for (int off = 1; off < 16; off <<= 1)
            mx[r] = fmaxf(mx[r], __shfl_xor(mx[r], off, 64));
    }

    // ---- issue all Vt fragment loads; latency hides under phase-2 exp work ---
    short8 vbr[7][4];
    #pragma unroll
    for (int kt = 0; kt < 7; ++kt) if (kt * 32 < Pcap) {
        int nq = (Pcap - kt * 32) >> 3;
        #pragma unroll
        for (int dt = 0; dt < 4; ++dt)
            vbr[kt][dt] = (quad < nq)
                ? *(const short8*)(Vg + (size_t)(dt * 16 + lm) * spad + kt * 32 + quad * 8)
                : zero8;
    }

    // -------- phase 2: exp + row-sum, exp'd scores written back in place ------
    float sum[4] = {0.f, 0.f, 0.f, 0.f};
    #pragma unroll
    for (int st = 0; st < 13; ++st) if (st < stmax) {
        int col = st * 16 + lm;
        if (col < PSTRF) {
            #pragma unroll
            for (int r = 0; r < 4; ++r) {
                int idx = (quad * 4 + r) * PSTRF + col;
                float p = __expf(Pw[idx] - mx[r]);
                sum[r] += p;
                Pw[idx] = p;
            }
        }
    }
    float rden[4];
    #pragma unroll
    for (int r = 0; r < 4; ++r) {
        #pragma unroll
        for (int off = 1; off < 16; off <<= 1)
            sum[r] += __shfl_xor(sum[r], off, 64);
        rden[r] = (sum[r] > 0.f) ? 1.0f / sum[r] : 0.f;
    }

    // -------- phase 3: PV, P from LDS f32 -> bf16 in-register, Vt from regs ---
    f32x4 ov[4] = {zerof, zerof, zerof, zerof};
    #pragma unroll
    for (int kt = 0; kt < 7; ++kt) if (kt * 32 < Pcap) {
        int k0 = kt * 32;
        int nq = (Pcap - k0) >> 3;
        short8 pa = zero8;
        if (quad < nq) {
            const float* prow = Pw + lm * PSTRF + k0 + quad * 8;
            f32x4 p0 = *(const f32x4*)prow;
            f32x4 p1 = *(const f32x4*)(prow + 4);
            pa[0] = (short)f2b(p0.x); pa[1] = (short)f2b(p0.y);
            pa[2] = (short)f2b(p0.z); pa[3] = (short)f2b(p0.w);
            pa[4] = (short)f2b(p1.x); pa[5] = (short)f2b(p1.y);
            pa[6] = (short)f2b(p1.z); pa[7] = (short)f2b(p1.w);
        }
        #pragma unroll
        for (int dt = 0; dt < 4; ++dt)
            ov[dt] = __builtin_amdgcn_mfma_f32_16x16x32_bf16(pa, vbr[kt][dt], ov[dt], 0, 0, 0);
    }

    // store O (in-place into Q slice)
    #pragma unroll
    for (int r = 0; r < 4; ++r) {
        int t = t0 + quad * 4 + r;
        if (t < T) {
            u16* orow = Qg + (size_t)t * ldq;
            #pragma unroll
            for (int dt = 0; dt < 4; ++dt)
                orow[dt * 16 + lm] = f2b(ov[dt][r] * rden[r]);
        }
    }
}

// ---------------- final logits: [rows,512](f32) @ ll_w[30,512]^T + b -> f32 ------
__global__ __launch_bounds__(256)
void logits_kernel(const float* __restrict__ X, const float* __restrict__ Wl,
                   const float* __restrict__ bl, float* __restrict__ out, int rows) {
    int idx = blockIdx.x * 256 + threadIdx.x;
    if (idx >= rows * V_SZ) return;
    int row = idx / V_SZ, v = idx % V_SZ;
    const f32x4* xr = (const f32x4*)(X + (size_t)row * D_MODEL);
    const f32x4* wr = (const f32x4*)(Wl + (size_t)v * D_MODEL);
    float acc = bl[v];
    #pragma unroll 4
    for (int k = 0; k < D_MODEL / 4; ++k) {
        f32x4 a = xr[k], w = wr[k];
        acc += a.x * w.x + a.y * w.y + a.z * w.z + a.w * w.w;
    }
    out[idx] = acc;
}

extern "C" void kernel_launch(void* const* d_in, const int* in_sizes, int n_in,
                              void* d_out, int out_size, void* d_ws, size_t ws_size,
                              hipStream_t stream) {
    const float* x          = (const float*)d_in[0];
    const float* y          = (const float*)d_in[1];
    const int*   x_mask     = (const int*)d_in[2];
    const int*   y_mask     = (const int*)d_in[3];
    const float* enc_qkv    = (const float*)d_in[4];
    const float* enc_proj_w = (const float*)d_in[5];
    const float* enc_proj_b = (const float*)d_in[6];
    const float* enc_ln1_g  = (const float*)d_in[7];
    const float* enc_ln1_b  = (const float*)d_in[8];
    const float* enc_ff_w1  = (const float*)d_in[9];
    const float* enc_ff_b1  = (const float*)d_in[10];
    const float* enc_ff_w2  = (const float*)d_in[11];
    const float* enc_ff_b2  = (const float*)d_in[12];
    const float* enc_ln2_g  = (const float*)d_in[13];
    const float* enc_ln2_b  = (const float*)d_in[14];
    const float* dec_sa_qkv    = (const float*)d_in[15];
    const float* dec_sa_proj_w = (const float*)d_in[16];
    const float* dec_sa_proj_b = (const float*)d_in[17];
    const float* dec_ln1_g  = (const float*)d_in[18];
    const float* dec_ln1_b  = (const float*)d_in[19];
    const float* dec_ca_qkv    = (const float*)d_in[20];
    const float* dec_ca_proj_w = (const float*)d_in[21];
    const float* dec_ca_proj_b = (const float*)d_in[22];
    const float* dec_ln2_g  = (const float*)d_in[23];
    const float* dec_ln2_b  = (const float*)d_in[24];
    const float* dec_ff_w1  = (const float*)d_in[25];
    const float* dec_ff_b1  = (const float*)d_in[26];
    const float* dec_ff_w2  = (const float*)d_in[27];
    const float* dec_ff_b2  = (const float*)d_in[28];
    const float* dec_ln3_g  = (const float*)d_in[29];
    const float* dec_ln3_b  = (const float*)d_in[30];
    const float* ll_w       = (const float*)d_in[31];
    const float* ll_b       = (const float*)d_in[32];

    const int ME = B_SZ * TX_SZ;   // 12800
    const int MD = B_SZ * TY_SZ;   // 6400
    const float rscale = 1.0f / sqrtf((float)D_MODEL);
    const int XWPR = (TX_SZ + 31) / 32;   // 7
    const int YWPR = (TY_SZ + 31) / 32;   // 4
    const int WQKV = 3 * D_MODEL * D_MODEL;
    const int WDD  = D_MODEL * D_MODEL;
    const int WFF  = DFF_SZ * D_MODEL;

    // ---- workspace ----
    char* base = (char*)d_ws;
    size_t off = 0;
    auto alloc = [&](size_t bytes) {
        void* p = base + off;
        off = (off + bytes + 63) & ~(size_t)63;
        return p;
    };
    float* A_enc = (float*)alloc((size_t)ME * D_MODEL * 4);
    float* A_dec = (float*)alloc((size_t)MD * D_MODEL * 4);
    float* N1f   = (float*)alloc((size_t)ME * D_MODEL * 4);
    u16*   N1b   = (u16*)  alloc((size_t)ME * D_MODEL * 2);
    u16*   NQb   = (u16*)  alloc((size_t)MD * D_MODEL * 2);
    u16*   BIG   = (u16*)  alloc((size_t)ME * DFF_SZ * 2);
    u16*   Vt    = (u16*)  alloc((size_t)B_SZ * H_SZ * 64 * 208 * 2);  // 13.6 MB
    unsigned* XMb = (unsigned*)alloc((size_t)ME * XWPR * 4);           // 358 KB
    unsigned* YMb = (unsigned*)alloc((size_t)MD * YWPR * 4);           // 102 KB
    // pre-cast bf16 weights (all layers, cast once per launch) -- 58.7 MB
    u16* Wall = (u16*)alloc(((size_t)4 * (2 * WQKV + 2 * WDD + 4 * WFF + WQKV + WDD)) * 2);
    u16* Wqkv_e   = Wall;
    u16* Wproj_e  = Wqkv_e   + (size_t)4 * WQKV;
    u16* Wff1_e   = Wproj_e  + (size_t)4 * WDD;
    u16* Wff2_e   = Wff1_e   + (size_t)4 * WFF;
    u16* Wqkv_sa  = Wff2_e   + (size_t)4 * WFF;
    u16* Wproj_sa = Wqkv_sa  + (size_t)4 * WQKV;
    u16* Wqkv_ca  = Wproj_sa + (size_t)4 * WDD;
    u16* Wproj_ca = Wqkv_ca  + (size_t)4 * WQKV;
    u16* Wff1_d   = Wproj_ca + (size_t)4 * WDD;
    u16* Wff2_d   = Wff1_d   + (size_t)4 * WFF;
    u16* QKVb = BIG;                        // [M,1536]
    u16* Hb   = BIG;                        // [M,2048]
    u16* KVb  = BIG;                        // [ME,1024]
    u16* Qca  = BIG + (size_t)ME * 1024;    // [MD,512]

    auto castw = [&](const float* in, u16* out, size_t n) {
        size_t n4 = n / 4;
        hipLaunchKernelGGL(castw_kernel, dim3((unsigned)((n4 + 255) / 256)), dim3(256), 0, stream,
                           in, out, (int)n4);
    };
    auto ln = [&](const float* in, const float* g, const float* b,
                  float* outf, u16* outb, int rows) {
        hipLaunchKernelGGL(ln_kernel, dim3(rows / 4), dim3(256), 0, stream, in, g, b, outf, outb, rows);
    };
    auto gemm = [&](const u16* A, int lda, const u16* W, int ldw, int M, int N, int K,
                    float* outf, int ldcf, u16* outb, int ldcb,
                    const float* bias, const float* resid, int ldr, int relu) {
        int blocks128 = (M / 128) * (N / 128);
        bool bn128 = (blocks128 >= 512) || (K >= 1024 && blocks128 >= 256);
        if (!bn128) {
            int NP = N / 64, nwg = (M / 128) * NP;
            int q8 = (nwg % 8 == 0) ? nwg / 8 : 0;
            hipLaunchKernelGGL((gemm_mfma_t<64>), dim3(nwg), dim3(256), 0, stream,
                               A, lda, W, ldw, outf, ldcf, outb, ldcb, bias, resid, ldr, relu,
                               K, NP, q8);
        } else {
            int NP = N / 128, nwg = (M / 128) * NP;
            int q8 = (nwg % 8 == 0) ? nwg / 8 : 0;
            hipLaunchKernelGGL((gemm_mfma_t<128>), dim3(nwg), dim3(256), 0, stream,
                               A, lda, W, ldw, outf, ldcf, outb, ldcb, bias, resid, ldr, relu,
                               K, NP, q8);
        }
    };
    auto vtrans = [&](const u16* V, int ldv, int S, int spad) {
        dim3 grid(B_SZ * H_SZ, (spad + 15) / 16);
        hipLaunchKernelGGL(vtrans_kernel, grid, dim3(256), 0, stream, V, ldv, Vt, S, spad);
    };
    auto attn = [&](u16* Q, int ldq, const u16* K, int ldk, int spad,
                    const unsigned* mbits, int mwpr, int T, int S, int causal) {
        dim3 grid(B_SZ * H_SZ, (T + 63) / 64);
        hipLaunchKernelGGL(attn_kernel, grid, dim3(256), 0, stream,
                           Q, ldq, K, ldk, Vt, spad, mbits, mwpr, T, S, causal, rscale);
    };

    // ---- once-per-launch preprocessing: mask bit-pack + weight pre-cast ----
    hipLaunchKernelGGL(maskpack_kernel, dim3((ME + 3) / 4), dim3(256), 0, stream,
                       x_mask, XMb, ME, TX_SZ, XWPR);
    hipLaunchKernelGGL(maskpack_kernel, dim3((MD + 3) / 4), dim3(256), 0, stream,
                       y_mask, YMb, MD, TY_SZ, YWPR);
    castw(enc_qkv,        Wqkv_e,   (size_t)4 * WQKV);
    castw(enc_proj_w,     Wproj_e,  (size_t)4 * WDD);
    castw(enc_ff_w1,      Wff1_e,   (size_t)4 * WFF);
    castw(enc_ff_w2,      Wff2_e,   (size_t)4 * WFF);
    castw(dec_sa_qkv,     Wqkv_sa,  (size_t)4 * WQKV);
    castw(dec_sa_proj_w,  Wproj_sa, (size_t)4 * WDD);
    castw(dec_ca_qkv,     Wqkv_ca,  (size_t)4 * WQKV);
    castw(dec_ca_proj_w,  Wproj_ca, (size_t)4 * WDD);
    castw(dec_ff_w1,      Wff1_d,   (size_t)4 * WFF);
    castw(dec_ff_w2,      Wff2_d,   (size_t)4 * WFF);

    // ---------------- encoder ----------------
    for (int l = 0; l < L_SZ; ++l) {
        const float* src = (l == 0) ? x : A_enc;
        ln(src, enc_ln1_g + l * D_MODEL, enc_ln1_b + l * D_MODEL, N1f, N1b, ME);
        gemm(N1b, 512, Wqkv_e + (size_t)l * WQKV, 512, ME, 1536, 512,
             nullptr, 0, QKVb, 1536, nullptr, nullptr, 0, 0);
        vtrans(QKVb + 1024, 1536, TX_SZ, 200);
        attn(QKVb, 1536, QKVb + 512, 1536, 200, XMb, XWPR, TX_SZ, TX_SZ, 0);
        gemm(QKVb, 1536, Wproj_e + (size_t)l * WDD, 512, ME, 512, 512,
             A_enc, 512, nullptr, 0, enc_proj_b + l * D_MODEL, N1f, 512, 0);
        ln(A_enc, enc_ln2_g + l * D_MODEL, enc_ln2_b + l * D_MODEL, nullptr, N1b, ME);
        gemm(N1b, 512, Wff1_e + (size_t)l * WFF, 512, ME, 2048, 512,
             nullptr, 0, Hb, 2048, enc_ff_b1 + l * DFF_SZ, nullptr, 0, 1);
        gemm(Hb, 2048, Wff2_e + (size_t)l * WFF, 2048, ME, 512, 2048,
             A_enc, 512, nullptr, 0, enc_ff_b2 + l * D_MODEL, A_enc, 512, 0);
    }

    // ---------------- decoder ----------------
    for (int l = 0; l < L_SZ; ++l) {
        const float* src = (l == 0) ? y : A_dec;
        ln(src, dec_ln1_g + l * D_MODEL, dec_ln1_b + l * D_MODEL, N1f, N1b, MD);
        gemm(N1b, 512, Wqkv_sa + (size_t)l * WQKV, 512, MD, 1536, 512,
             nullptr, 0, QKVb, 1536, nullptr, nullptr, 0, 0);
        vtrans(QKVb + 1024, 1536, TY_SZ, 104);
        attn(QKVb, 1536, QKVb + 512, 1536, 104, YMb, YWPR, TY_SZ, TY_SZ, 1);
        gemm(QKVb, 1536, Wproj_sa + (size_t)l * WDD, 512, MD, 512, 512,
             A_dec, 512, nullptr, 0, dec_sa_proj_b + l * D_MODEL, N1f, 512, 0);
        // cross-attention
        ln(A_enc, dec_ln2_g + l * D_MODEL, dec_ln2_b + l * D_MODEL, nullptr, N1b, ME);
        ln(A_dec, dec_ln2_g + l * D_MODEL, dec_ln2_b + l * D_MODEL, N1f, NQb, MD);
        gemm(NQb, 512, Wqkv_ca + (size_t)l * WQKV, 512, MD, 512, 512,
             nullptr, 0, Qca, 512, nullptr, nullptr, 0, 0);
        gemm(N1b, 512, Wqkv_ca + (size_t)l * WQKV + WDD, 512, ME, 1024, 512,
             nullptr, 0, KVb, 1024, nullptr, nullptr, 0, 0);
        vtrans(KVb + 512, 1024, TX_SZ, 200);
        attn(Qca, 512, KVb, 1024, 200, nullptr, XWPR, TY_SZ, TX_SZ, 0);
        gemm(Qca, 512, Wproj_ca + (size_t)l * WDD, 512, MD, 512, 512,
             A_dec, 512, nullptr, 0, dec_ca_proj_b + l * D_MODEL, N1f, 512, 0);
        // FF
        ln(A_dec, dec_ln3_g + l * D_MODEL, dec_ln3_b + l * D_MODEL, nullptr, N1b, MD);
        gemm(N1b, 512, Wff1_d + (size_t)l * WFF, 512, MD, 2048, 512,
             nullptr, 0, Hb, 2048, dec_ff_b1 + l * DFF_SZ, nullptr, 0, 1);
        gemm(Hb, 2048, Wff2_d + (size_t)l * WFF, 2048, MD, 512, 2048,
             A_dec, 512, nullptr, 0, dec_ff_b2 + l * D_MODEL, A_dec, 512, 0);
    }

    // ---------------- final projection ----------------
    {
        int total = MD * V_SZ;
        hipLaunchKernelGGL(logits_kernel, dim3((total + 255) / 256), dim3(256), 0, stream,
                           A_dec, ll_w, ll_b, (float*)d_out, MD);
    }
    (void)in_sizes; (void)n_in; (void)out_size; (void)ws_size;
}

// Round 9
// 2648.141 us; speedup vs baseline: 1.0282x; 1.0282x over previous
//
#include <hip/hip_runtime.h>
#include <math.h>

#define B_SZ   64
#define TX_SZ  200
#define TY_SZ  100
#define D_MODEL 512
#define H_SZ   8
#define DK_SZ  64
#define DFF_SZ 2048
#define L_SZ   4
#define V_SZ   30

#define NEG_BIG -1.0e30f

// attention P-scratch: f32 scores, per-wave region [16 rows][PSTRF cols].
// PSTRF=204: 4 waves x 16 x 204 x 4B = 52224 B -> 3 blocks/CU.
#define PSTRF 204
#define ATT_LDSF (4 * 16 * PSTRF)

typedef unsigned short u16;
typedef __attribute__((ext_vector_type(8))) short short8;
typedef __attribute__((ext_vector_type(4))) short short4t;
typedef __attribute__((ext_vector_type(4))) float f32x4;
typedef __attribute__((ext_vector_type(4))) unsigned short u16x4;

__device__ __forceinline__ float b2f(u16 h) {
    union { unsigned int u; float f; } v; v.u = ((unsigned int)h) << 16; return v.f;
}
__device__ __forceinline__ u16 f2b(float f) {
    union { float f; unsigned int u; } v; v.f = f;
    unsigned int r = v.u + 0x7fffu + ((v.u >> 16) & 1u);
    return (u16)(r >> 16);
}

#define GLD16(gp, lp) __builtin_amdgcn_global_load_lds( \
    (const __attribute__((address_space(1))) unsigned int*)(gp), \
    (__attribute__((address_space(3))) unsigned int*)(lp), 16, 0, 0)

// ---------------- cast f32 -> bf16, 4 elems/thread ----------------
__global__ __launch_bounds__(256)
void castw_kernel(const float* __restrict__ in, u16* __restrict__ out, int n4) {
    int i = blockIdx.x * 256 + threadIdx.x;
    if (i < n4) {
        f32x4 v = ((const f32x4*)in)[i];
        u16x4 o;
        o.x = f2b(v.x); o.y = f2b(v.y); o.z = f2b(v.z); o.w = f2b(v.w);
        ((u16x4*)out)[i] = o;
    }
}

// ---------------- bit-pack mask rows: [rows][S] int32 -> [rows][wpr] u32 ------
// bit = 1 iff mask == 1 (i.e. position is masked out). Wave per row, ballot.
__global__ __launch_bounds__(256)
void maskpack_kernel(const int* __restrict__ mask, unsigned* __restrict__ bits,
                     int rows, int S, int wpr) {
    int row = blockIdx.x * 4 + (threadIdx.x >> 6);
    int lane = threadIdx.x & 63;
    if (row >= rows) return;
    const int* mr = mask + (size_t)row * S;
    unsigned* br = bits + (size_t)row * wpr;
    for (int s0 = 0; s0 < S; s0 += 64) {
        int s = s0 + lane;
        int v = (s < S) ? mr[s] : 0;
        unsigned long long bm = __ballot(v == 1);
        if (lane == 0) {
            br[s0 >> 5] = (unsigned)bm;
            if ((s0 >> 5) + 1 < wpr) br[(s0 >> 5) + 1] = (unsigned)(bm >> 32);
        }
    }
}

// ---------------- transpose V slice -> Vt[(b*8+h)*64 + d][spad] ---------------
__global__ __launch_bounds__(256)
void vtrans_kernel(const u16* __restrict__ V, int ldv, u16* __restrict__ Vt,
                   int S, int spad) {
    __shared__ u16 t[16][72];
    const int bh = blockIdx.x;
    const int s0 = blockIdx.y * 16;
    const int h = bh & 7, b = bh >> 3;
    const int tid = threadIdx.x;
    {
        int sl = tid >> 4, c4 = (tid & 15) * 4;
        int s = s0 + sl;
        int ss = (s < S) ? s : S - 1;
        u16x4 v = *(const u16x4*)(V + (size_t)(b * S + ss) * ldv + h * 64 + c4);
        *(u16x4*)&t[sl][c4] = v;
    }
    __syncthreads();
    int d = tid >> 2, j0 = (tid & 3) * 4;
    if (s0 + j0 < spad) {
        u16x4 o;
        o.x = (s0 + j0 + 0 < S) ? t[j0 + 0][d] : (u16)0;
        o.y = (s0 + j0 + 1 < S) ? t[j0 + 1][d] : (u16)0;
        o.z = (s0 + j0 + 2 < S) ? t[j0 + 2][d] : (u16)0;
        o.w = (s0 + j0 + 3 < S) ? t[j0 + 3][d] : (u16)0;
        *(u16x4*)(Vt + ((size_t)bh * 64 + d) * spad + s0 + j0) = o;
    }
}

// ---------------- LayerNorm (rows x 512): wave per row, no barriers ----------
__global__ __launch_bounds__(256)
void ln_kernel(const float* __restrict__ in, const float* __restrict__ g,
               const float* __restrict__ b, float* outf, u16* outb, int rows) {
    int row = blockIdx.x * 4 + (threadIdx.x >> 6);
    int lane = threadIdx.x & 63;
    if (row >= rows) return;
    const f32x4* xr = (const f32x4*)(in + (size_t)row * D_MODEL);
    f32x4 v0 = xr[lane];
    f32x4 v1 = xr[lane + 64];
    float s  = v0.x + v0.y + v0.z + v0.w + v1.x + v1.y + v1.z + v1.w;
    float ss = v0.x*v0.x + v0.y*v0.y + v0.z*v0.z + v0.w*v0.w
             + v1.x*v1.x + v1.y*v1.y + v1.z*v1.z + v1.w*v1.w;
    #pragma unroll
    for (int off = 1; off < 64; off <<= 1) {
        s  += __shfl_xor(s, off, 64);
        ss += __shfl_xor(ss, off, 64);
    }
    float mean = s * (1.0f / D_MODEL);
    float var  = ss * (1.0f / D_MODEL) - mean * mean;
    float rstd = rsqrtf(var + 1e-5f);
    f32x4 g0 = ((const f32x4*)g)[lane],      g1 = ((const f32x4*)g)[lane + 64];
    f32x4 b0 = ((const f32x4*)b)[lane],      b1 = ((const f32x4*)b)[lane + 64];
    f32x4 o0, o1;
    o0.x = (v0.x - mean) * rstd * g0.x + b0.x;
    o0.y = (v0.y - mean) * rstd * g0.y + b0.y;
    o0.z = (v0.z - mean) * rstd * g0.z + b0.z;
    o0.w = (v0.w - mean) * rstd * g0.w + b0.w;
    o1.x = (v1.x - mean) * rstd * g1.x + b1.x;
    o1.y = (v1.y - mean) * rstd * g1.y + b1.y;
    o1.z = (v1.z - mean) * rstd * g1.z + b1.z;
    o1.w = (v1.w - mean) * rstd * g1.w + b1.w;
    if (outf) {
        f32x4* of = (f32x4*)(outf + (size_t)row * D_MODEL);
        of[lane] = o0; of[lane + 64] = o1;
    }
    if (outb) {
        u16x4* ob = (u16x4*)(outb + (size_t)row * D_MODEL);
        u16x4 p0, p1;
        p0.x = f2b(o0.x); p0.y = f2b(o0.y); p0.z = f2b(o0.z); p0.w = f2b(o0.w);
        p1.x = f2b(o1.x); p1.y = f2b(o1.y); p1.z = f2b(o1.z); p1.w = f2b(o1.w);
        ob[lane] = p0; ob[lane + 64] = p1;
    }
}

// ---------------- MFMA GEMM v3: counted-vmcnt pipelined K-loop ----------------
// Double-buffered LDS; stage tile t+1, then wait ONLY for tile t's loads
// (s_waitcnt vmcnt(LPS), never 0 in-loop) + raw s_barrier. The prefetch for
// t+1 stays in flight across the barrier (T3/T4 recipe). Second barrier (no
// drain) protects buf before overwrite. sched_barrier(0) pins ordering.
template<int BN>
__global__ __launch_bounds__(256)
void gemm_mfma_t(const u16* __restrict__ A, int lda,
                 const u16* __restrict__ W, int ldw,
                 float* outf, int ldcf, u16* outb, int ldcb,
                 const float* __restrict__ bias,
                 const float* __restrict__ resid, int ldr,
                 int relu, int K, int NP, int q8) {
    constexpr int NJ = BN / 32;
    __shared__ u16 Alds[2][128 * 32];
    __shared__ u16 Blds[2][BN * 32];
    const int tid  = threadIdx.x;
    const int wave = tid >> 6, lane = tid & 63;
    const int lr = lane & 15, lq = lane >> 4;
    const int wm = (wave >> 1) * 64, wn = (wave & 1) * (BN / 2);
    const int bid = blockIdx.x;
    const int sid = q8 ? ((bid & 7) * q8 + (bid >> 3)) : bid;
    const int m0 = (sid / NP) * 128, n0 = (sid % NP) * BN;
    const int grow = tid >> 2;
    const int gcol = (tid & 3) * 8;
    const int woff = wave * 512;

    f32x4 zero = {0.f, 0.f, 0.f, 0.f};
    f32x4 acc[4][NJ];
    #pragma unroll
    for (int i = 0; i < 4; ++i)
        #pragma unroll
        for (int j = 0; j < NJ; ++j) acc[i][j] = zero;

    const u16* Ag = A + (size_t)m0 * lda;
    const u16* Wg = W + (size_t)n0 * ldw;

    auto stage = [&](int buf, int k0) {
        GLD16(Ag + (size_t)grow * lda + k0 + gcol,        &Alds[buf][woff]);
        GLD16(Ag + (size_t)(64 + grow) * lda + k0 + gcol, &Alds[buf][2048 + woff]);
        GLD16(Wg + (size_t)grow * ldw + k0 + gcol,        &Blds[buf][woff]);
        if (BN == 128)
            GLD16(Wg + (size_t)(64 + grow) * ldw + k0 + gcol, &Blds[buf][2048 + woff]);
    };

    stage(0, 0);                       // loads for tile 0 in flight
    const int nt = K >> 5;
    int cur = 0;
    for (int t = 0; t < nt; ++t) {
        if (t + 1 < nt) {
            stage(cur ^ 1, (t + 1) << 5);          // issue next tile's loads
            // wait for tile t's loads only; keep the LPS newest in flight
            if constexpr (BN == 128)
                asm volatile("s_waitcnt vmcnt(4)" ::: "memory");
            else
                asm volatile("s_waitcnt vmcnt(3)" ::: "memory");
        } else {
            asm volatile("s_waitcnt vmcnt(0)" ::: "memory");
        }
        __builtin_amdgcn_s_barrier();              // all waves: buf[cur] ready
        __builtin_amdgcn_sched_barrier(0);
        short8 af[4], bfr[NJ];
        #pragma unroll
        for (int i = 0; i < 4; ++i)
            af[i] = *(const short8*)&Alds[cur][(wm + i * 16 + lr) * 32 + lq * 8];
        #pragma unroll
        for (int j = 0; j < NJ; ++j)
            bfr[j] = *(const short8*)&Blds[cur][(wn + j * 16 + lr) * 32 + lq * 8];
        #pragma unroll
        for (int i = 0; i < 4; ++i)
            #pragma unroll
            for (int j = 0; j < NJ; ++j)
                acc[i][j] = __builtin_amdgcn_mfma_f32_16x16x32_bf16(af[i], bfr[j], acc[i][j], 0, 0, 0);
        __builtin_amdgcn_s_barrier();              // readers done before overwrite
        __builtin_amdgcn_sched_barrier(0);
        cur ^= 1;
    }

    #pragma unroll
    for (int i = 0; i < 4; ++i) {
        #pragma unroll
        for (int r = 0; r < 4; ++r) {
            int m = m0 + wm + i * 16 + lq * 4 + r;
            #pragma unroll
            for (int j = 0; j < NJ; ++j) {
                int n = n0 + wn + j * 16 + lr;
                float c = acc[i][j][r];
                if (bias)  c += bias[n];
                if (resid) c += resid[(size_t)m * ldr + n];
                if (relu)  c = fmaxf(c, 0.f);
                if (outf) outf[(size_t)m * ldcf + n] = c;
                if (outb) outb[(size_t)m * ldcb + n] = f2b(c);
            }
        }
    }
}

// ---------------- attention v10: batched-prefetch flash -----------------------
// Grid (B*H, T-tiles), 4 waves/block, one 16-row t-tile per wave, no barriers.
// All mask words (mrow[4][7]) and all K fragments (kb[13][2]) are prefetched
// BEFORE any MFMA -> one latency round instead of 13 serialized batches.
// Vt fragments (vbr[7][4]) are issued before phase 2 so their latency hides
// under the exp/softmax VALU work. All arrays statically indexed.
// Note: s>>5 == st>>1 (s = st*16+lm, lm<16), so mask word index is static.
__global__ __launch_bounds__(256, 2)
void attn_kernel(u16* __restrict__ Q, int ldq, const u16* __restrict__ K, int ldk,
                 const u16* __restrict__ Vt, int spad,
                 const unsigned* __restrict__ mbits, int mwpr,
                 int T, int S, int causal, float rscale) {
    __shared__ float Pl[ATT_LDSF];
    const int bh = blockIdx.x, tile = blockIdx.y;
    const int h = bh & 7, b = bh >> 3;
    const int tid = threadIdx.x, wave = tid >> 6, lane = tid & 63;
    const int lm = lane & 15, quad = lane >> 4;
    const int t0 = tile * 64 + wave * 16;
    if (t0 >= T) return;

    const u16* Kg = K + (size_t)(b * S) * ldk + h * DK_SZ;
    const u16* Vg = Vt + (size_t)bh * 64 * spad;
    u16* Qg = Q + (size_t)(b * T) * ldq + h * DK_SZ;

    const int stiles = (S + 15) >> 4;
    int stmax = stiles;
    if (causal) { int c = (t0 >> 4) + 1; if (c < stmax) stmax = c; }
    const int Scap8 = (S + 7) & ~7;
    int Pcap = stmax * 16; if (Pcap > Scap8) Pcap = Scap8;

    float* Pw = Pl + wave * (16 * PSTRF);

    // ---- prefetch: Q, all mask words, all K fragments (one latency round) ----
    int qr = t0 + lm; if (qr >= T) qr = T - 1;
    const u16* qrow = Qg + (size_t)qr * ldq;
    short8 qa0 = *(const short8*)(qrow + quad * 8);
    short8 qa1 = *(const short8*)(qrow + 32 + quad * 8);

    unsigned mrow[4][7];
    if (mbits) {
        #pragma unroll
        for (int r = 0; r < 4; ++r) {
            int t = t0 + quad * 4 + r;
            int tc = (t < T) ? t : T - 1;
            const unsigned* mp = mbits + (size_t)(b * T + tc) * mwpr;
            #pragma unroll
            for (int w = 0; w < 7; ++w)
                if (w < mwpr) mrow[r][w] = mp[w];
        }
    }

    short8 kb[13][2];
    #pragma unroll
    for (int st = 0; st < 13; ++st) if (st < stmax) {
        int srow = st * 16 + lm; if (srow >= S) srow = S - 1;
        const u16* kp = Kg + (size_t)srow * ldk + quad * 8;
        kb[st][0] = *(const short8*)kp;
        kb[st][1] = *(const short8*)(kp + 32);
    }

    const short8 zero8 = {0, 0, 0, 0, 0, 0, 0, 0};
    const f32x4 zerof = {0.f, 0.f, 0.f, 0.f};

    // -------- phase 1: QK^T + mask/scale + running max, scores -> LDS f32 -----
    float mx[4] = {NEG_BIG, NEG_BIG, NEG_BIG, NEG_BIG};
    #pragma unroll
    for (int st = 0; st < 13; ++st) if (st < stmax) {
        f32x4 c = zerof;
        c = __builtin_amdgcn_mfma_f32_16x16x32_bf16(qa0, kb[st][0], c, 0, 0, 0);
        c = __builtin_amdgcn_mfma_f32_16x16x32_bf16(qa1, kb[st][1], c, 0, 0, 0);
        int s = st * 16 + lm;
        #pragma unroll
        for (int r = 0; r < 4; ++r) {
            int t = t0 + quad * 4 + r;
            bool valid = (s < S) && (!causal || s <= t);
            if (valid && mbits)
                valid = ((mrow[r][st >> 1] >> (((st & 1) << 4) + lm)) & 1u) == 0;
            float f = valid ? c[r] * rscale : NEG_BIG;
            mx[r] = fmaxf(mx[r], f);
            if (s < PSTRF) Pw[(quad * 4 + r) * PSTRF + s] = f;
        }
    }
    #pragma unroll
    for (int r = 0; r < 4; ++r) {
        #pragma unroll
        for (int off = 1; off < 16; off <<= 1)
            mx[r] = fmaxf(mx[r], __shfl_xor(mx[r], off, 64));
    }

    // ---- issue all Vt fragment loads; latency hides under phase-2 exp work ---
    short8 vbr[7][4];
    #pragma unroll
    for (int kt = 0; kt < 7; ++kt) if (kt * 32 < Pcap) {
        int nq = (Pcap - kt * 32) >> 3;
        #pragma unroll
        for (int dt = 0; dt < 4; ++dt)
            vbr[kt][dt] = (quad < nq)
                ? *(const short8*)(Vg + (size_t)(dt * 16 + lm) * spad + kt * 32 + quad * 8)
                : zero8;
    }

    // -------- phase 2: exp + row-sum, exp'd scores written back in place ------
    float sum[4] = {0.f, 0.f, 0.f, 0.f};
    #pragma unroll
    for (int st = 0; st < 13; ++st) if (st < stmax) {
        int col = st * 16 + lm;
        if (col < PSTRF) {
            #pragma unroll
            for (int r = 0; r < 4; ++r) {
                int idx = (quad * 4 + r) * PSTRF + col;
                float p = __expf(Pw[idx] - mx[r]);
                sum[r] += p;
                Pw[idx] = p;
            }
        }
    }
    float rden[4];
    #pragma unroll
    for (int r = 0; r < 4; ++r) {
        #pragma unroll
        for (int off = 1; off < 16; off <<= 1)
            sum[r] += __shfl_xor(sum[r], off, 64);
        rden[r] = (sum[r] > 0.f) ? 1.0f / sum[r] : 0.f;
    }

    // -------- phase 3: PV, P from LDS f32 -> bf16 in-register, Vt from regs ---
    f32x4 ov[4] = {zerof, zerof, zerof, zerof};
    #pragma unroll
    for (int kt = 0; kt < 7; ++kt) if (kt * 32 < Pcap) {
        int k0 = kt * 32;
        int nq = (Pcap - k0) >> 3;
        short8 pa = zero8;
        if (quad < nq) {
            const float* prow = Pw + lm * PSTRF + k0 + quad * 8;
            f32x4 p0 = *(const f32x4*)prow;
            f32x4 p1 = *(const f32x4*)(prow + 4);
            pa[0] = (short)f2b(p0.x); pa[1] = (short)f2b(p0.y);
            pa[2] = (short)f2b(p0.z); pa[3] = (short)f2b(p0.w);
            pa[4] = (short)f2b(p1.x); pa[5] = (short)f2b(p1.y);
            pa[6] = (short)f2b(p1.z); pa[7] = (short)f2b(p1.w);
        }
        #pragma unroll
        for (int dt = 0; dt < 4; ++dt)
            ov[dt] = __builtin_amdgcn_mfma_f32_16x16x32_bf16(pa, vbr[kt][dt], ov[dt], 0, 0, 0);
    }

    // store O (in-place into Q slice)
    #pragma unroll
    for (int r = 0; r < 4; ++r) {
        int t = t0 + quad * 4 + r;
        if (t < T) {
            u16* orow = Qg + (size_t)t * ldq;
            #pragma unroll
            for (int dt = 0; dt < 4; ++dt)
                orow[dt * 16 + lm] = f2b(ov[dt][r] * rden[r]);
        }
    }
}

// ---------------- final logits: [rows,512](f32) @ ll_w[30,512]^T + b -> f32 ------
__global__ __launch_bounds__(256)
void logits_kernel(const float* __restrict__ X, const float* __restrict__ Wl,
                   const float* __restrict__ bl, float* __restrict__ out, int rows) {
    int idx = blockIdx.x * 256 + threadIdx.x;
    if (idx >= rows * V_SZ) return;
    int row = idx / V_SZ, v = idx % V_SZ;
    const f32x4* xr = (const f32x4*)(X + (size_t)row * D_MODEL);
    const f32x4* wr = (const f32x4*)(Wl + (size_t)v * D_MODEL);
    float acc = bl[v];
    #pragma unroll 4
    for (int k = 0; k < D_MODEL / 4; ++k) {
        f32x4 a = xr[k], w = wr[k];
        acc += a.x * w.x + a.y * w.y + a.z * w.z + a.w * w.w;
    }
    out[idx] = acc;
}

extern "C" void kernel_launch(void* const* d_in, const int* in_sizes, int n_in,
                              void* d_out, int out_size, void* d_ws, size_t ws_size,
                              hipStream_t stream) {
    const float* x          = (const float*)d_in[0];
    const float* y          = (const float*)d_in[1];
    const int*   x_mask     = (const int*)d_in[2];
    const int*   y_mask     = (const int*)d_in[3];
    const float* enc_qkv    = (const float*)d_in[4];
    const float* enc_proj_w = (const float*)d_in[5];
    const float* enc_proj_b = (const float*)d_in[6];
    const float* enc_ln1_g  = (const float*)d_in[7];
    const float* enc_ln1_b  = (const float*)d_in[8];
    const float* enc_ff_w1  = (const float*)d_in[9];
    const float* enc_ff_b1  = (const float*)d_in[10];
    const float* enc_ff_w2  = (const float*)d_in[11];
    const float* enc_ff_b2  = (const float*)d_in[12];
    const float* enc_ln2_g  = (const float*)d_in[13];
    const float* enc_ln2_b  = (const float*)d_in[14];
    const float* dec_sa_qkv    = (const float*)d_in[15];
    const float* dec_sa_proj_w = (const float*)d_in[16];
    const float* dec_sa_proj_b = (const float*)d_in[17];
    const float* dec_ln1_g  = (const float*)d_in[18];
    const float* dec_ln1_b  = (const float*)d_in[19];
    const float* dec_ca_qkv    = (const float*)d_in[20];
    const float* dec_ca_proj_w = (const float*)d_in[21];
    const float* dec_ca_proj_b = (const float*)d_in[22];
    const float* dec_ln2_g  = (const float*)d_in[23];
    const float* dec_ln2_b  = (const float*)d_in[24];
    const float* dec_ff_w1  = (const float*)d_in[25];
    const float* dec_ff_b1  = (const float*)d_in[26];
    const float* dec_ff_w2  = (const float*)d_in[27];
    const float* dec_ff_b2  = (const float*)d_in[28];
    const float* dec_ln3_g  = (const float*)d_in[29];
    const float* dec_ln3_b  = (const float*)d_in[30];
    const float* ll_w       = (const float*)d_in[31];
    const float* ll_b       = (const float*)d_in[32];

    const int ME = B_SZ * TX_SZ;   // 12800
    const int MD = B_SZ * TY_SZ;   // 6400
    const float rscale = 1.0f / sqrtf((float)D_MODEL);
    const int XWPR = (TX_SZ + 31) / 32;   // 7
    const int YWPR = (TY_SZ + 31) / 32;   // 4
    const int WQKV = 3 * D_MODEL * D_MODEL;
    const int WDD  = D_MODEL * D_MODEL;
    const int WFF  = DFF_SZ * D_MODEL;

    // ---- workspace ----
    char* base = (char*)d_ws;
    size_t off = 0;
    auto alloc = [&](size_t bytes) {
        void* p = base + off;
        off = (off + bytes + 63) & ~(size_t)63;
        return p;
    };
    float* A_enc = (float*)alloc((size_t)ME * D_MODEL * 4);
    float* A_dec = (float*)alloc((size_t)MD * D_MODEL * 4);
    float* N1f   = (float*)alloc((size_t)ME * D_MODEL * 4);
    u16*   N1b   = (u16*)  alloc((size_t)ME * D_MODEL * 2);
    u16*   NQb   = (u16*)  alloc((size_t)MD * D_MODEL * 2);
    u16*   BIG   = (u16*)  alloc((size_t)ME * DFF_SZ * 2);
    u16*   Vt    = (u16*)  alloc((size_t)B_SZ * H_SZ * 64 * 208 * 2);  // 13.6 MB
    unsigned* XMb = (unsigned*)alloc((size_t)ME * XWPR * 4);           // 358 KB
    unsigned* YMb = (unsigned*)alloc((size_t)MD * YWPR * 4);           // 102 KB
    // pre-cast bf16 weights (all layers, cast once per launch) -- 58.7 MB
    u16* Wall = (u16*)alloc(((size_t)4 * (2 * WQKV + 2 * WDD + 4 * WFF + WQKV + WDD)) * 2);
    u16* Wqkv_e   = Wall;
    u16* Wproj_e  = Wqkv_e   + (size_t)4 * WQKV;
    u16* Wff1_e   = Wproj_e  + (size_t)4 * WDD;
    u16* Wff2_e   = Wff1_e   + (size_t)4 * WFF;
    u16* Wqkv_sa  = Wff2_e   + (size_t)4 * WFF;
    u16* Wproj_sa = Wqkv_sa  + (size_t)4 * WQKV;
    u16* Wqkv_ca  = Wproj_sa + (size_t)4 * WDD;
    u16* Wproj_ca = Wqkv_ca  + (size_t)4 * WQKV;
    u16* Wff1_d   = Wproj_ca + (size_t)4 * WDD;
    u16* Wff2_d   = Wff1_d   + (size_t)4 * WFF;
    u16* QKVb = BIG;                        // [M,1536]
    u16* Hb   = BIG;                        // [M,2048]
    u16* KVb  = BIG;                        // [ME,1024]
    u16* Qca  = BIG + (size_t)ME * 1024;    // [MD,512]

    auto castw = [&](const float* in, u16* out, size_t n) {
        size_t n4 = n / 4;
        hipLaunchKernelGGL(castw_kernel, dim3((unsigned)((n4 + 255) / 256)), dim3(256), 0, stream,
                           in, out, (int)n4);
    };
    auto ln = [&](const float* in, const float* g, const float* b,
                  float* outf, u16* outb, int rows) {
        hipLaunchKernelGGL(ln_kernel, dim3(rows / 4), dim3(256), 0, stream, in, g, b, outf, outb, rows);
    };
    auto gemm = [&](const u16* A, int lda, const u16* W, int ldw, int M, int N, int K,
                    float* outf, int ldcf, u16* outb, int ldcb,
                    const float* bias, const float* resid, int ldr, int relu) {
        int blocks128 = (M / 128) * (N / 128);
        if (blocks128 < 512) {
            int NP = N / 64, nwg = (M / 128) * NP;
            int q8 = (nwg % 8 == 0) ? nwg / 8 : 0;
            hipLaunchKernelGGL((gemm_mfma_t<64>), dim3(nwg), dim3(256), 0, stream,
                               A, lda, W, ldw, outf, ldcf, outb, ldcb, bias, resid, ldr, relu,
                               K, NP, q8);
        } else {
            int NP = N / 128, nwg = (M / 128) * NP;
            int q8 = (nwg % 8 == 0) ? nwg / 8 : 0;
            hipLaunchKernelGGL((gemm_mfma_t<128>), dim3(nwg), dim3(256), 0, stream,
                               A, lda, W, ldw, outf, ldcf, outb, ldcb, bias, resid, ldr, relu,
                               K, NP, q8);
        }
    };
    auto vtrans = [&](const u16* V, int ldv, int S, int spad) {
        dim3 grid(B_SZ * H_SZ, (spad + 15) / 16);
        hipLaunchKernelGGL(vtrans_kernel, grid, dim3(256), 0, stream, V, ldv, Vt, S, spad);
    };
    auto attn = [&](u16* Q, int ldq, const u16* K, int ldk, int spad,
                    const unsigned* mbits, int mwpr, int T, int S, int causal) {
        dim3 grid(B_SZ * H_SZ, (T + 63) / 64);
        hipLaunchKernelGGL(attn_kernel, grid, dim3(256), 0, stream,
                           Q, ldq, K, ldk, Vt, spad, mbits, mwpr, T, S, causal, rscale);
    };

    // ---- once-per-launch preprocessing: mask bit-pack + weight pre-cast ----
    hipLaunchKernelGGL(maskpack_kernel, dim3((ME + 3) / 4), dim3(256), 0, stream,
                       x_mask, XMb, ME, TX_SZ, XWPR);
    hipLaunchKernelGGL(maskpack_kernel, dim3((MD + 3) / 4), dim3(256), 0, stream,
                       y_mask, YMb, MD, TY_SZ, YWPR);
    castw(enc_qkv,        Wqkv_e,   (size_t)4 * WQKV);
    castw(enc_proj_w,     Wproj_e,  (size_t)4 * WDD);
    castw(enc_ff_w1,      Wff1_e,   (size_t)4 * WFF);
    castw(enc_ff_w2,      Wff2_e,   (size_t)4 * WFF);
    castw(dec_sa_qkv,     Wqkv_sa,  (size_t)4 * WQKV);
    castw(dec_sa_proj_w,  Wproj_sa, (size_t)4 * WDD);
    castw(dec_ca_qkv,     Wqkv_ca,  (size_t)4 * WQKV);
    castw(dec_ca_proj_w,  Wproj_ca, (size_t)4 * WDD);
    castw(dec_ff_w1,      Wff1_d,   (size_t)4 * WFF);
    castw(dec_ff_w2,      Wff2_d,   (size_t)4 * WFF);

    // ---------------- encoder ----------------
    for (int l = 0; l < L_SZ; ++l) {
        const float* src = (l == 0) ? x : A_enc;
        ln(src, enc_ln1_g + l * D_MODEL, enc_ln1_b + l * D_MODEL, N1f, N1b, ME);
        gemm(N1b, 512, Wqkv_e + (size_t)l * WQKV, 512, ME, 1536, 512,
             nullptr, 0, QKVb, 1536, nullptr, nullptr, 0, 0);
        vtrans(QKVb + 1024, 1536, TX_SZ, 200);
        attn(QKVb, 1536, QKVb + 512, 1536, 200, XMb, XWPR, TX_SZ, TX_SZ, 0);
        gemm(QKVb, 1536, Wproj_e + (size_t)l * WDD, 512, ME, 512, 512,
             A_enc, 512, nullptr, 0, enc_proj_b + l * D_MODEL, N1f, 512, 0);
        ln(A_enc, enc_ln2_g + l * D_MODEL, enc_ln2_b + l * D_MODEL, nullptr, N1b, ME);
        gemm(N1b, 512, Wff1_e + (size_t)l * WFF, 512, ME, 2048, 512,
             nullptr, 0, Hb, 2048, enc_ff_b1 + l * DFF_SZ, nullptr, 0, 1);
        gemm(Hb, 2048, Wff2_e + (size_t)l * WFF, 2048, ME, 512, 2048,
             A_enc, 512, nullptr, 0, enc_ff_b2 + l * D_MODEL, A_enc, 512, 0);
    }

    // ---------------- decoder ----------------
    for (int l = 0; l < L_SZ; ++l) {
        const float* src = (l == 0) ? y : A_dec;
        ln(src, dec_ln1_g + l * D_MODEL, dec_ln1_b + l * D_MODEL, N1f, N1b, MD);
        gemm(N1b, 512, Wqkv_sa + (size_t)l * WQKV, 512, MD, 1536, 512,
             nullptr, 0, QKVb, 1536, nullptr, nullptr, 0, 0);
        vtrans(QKVb + 1024, 1536, TY_SZ, 104);
        attn(QKVb, 1536, QKVb + 512, 1536, 104, YMb, YWPR, TY_SZ, TY_SZ, 1);
        gemm(QKVb, 1536, Wproj_sa + (size_t)l * WDD, 512, MD, 512, 512,
             A_dec, 512, nullptr, 0, dec_sa_proj_b + l * D_MODEL, N1f, 512, 0);
        // cross-attention
        ln(A_enc, dec_ln2_g + l * D_MODEL, dec_ln2_b + l * D_MODEL, nullptr, N1b, ME);
        ln(A_dec, dec_ln2_g + l * D_MODEL, dec_ln2_b + l * D_MODEL, N1f, NQb, MD);
        gemm(NQb, 512, Wqkv_ca + (size_t)l * WQKV, 512, MD, 512, 512,
             nullptr, 0, Qca, 512, nullptr, nullptr, 0, 0);
        gemm(N1b, 512, Wqkv_ca + (size_t)l * WQKV + WDD, 512, ME, 1024, 512,
             nullptr, 0, KVb, 1024, nullptr, nullptr, 0, 0);
        vtrans(KVb + 512, 1024, TX_SZ, 200);
        attn(Qca, 512, KVb, 1024, 200, nullptr, XWPR, TY_SZ, TX_SZ, 0);
        gemm(Qca, 512, Wproj_ca + (size_t)l * WDD, 512, MD, 512, 512,
             A_dec, 512, nullptr, 0, dec_ca_proj_b + l * D_MODEL, N1f, 512, 0);
        // FF
        ln(A_dec, dec_ln3_g + l * D_MODEL, dec_ln3_b + l * D_MODEL, nullptr, N1b, MD);
        gemm(N1b, 512, Wff1_d + (size_t)l * WFF, 512, MD, 2048, 512,
             nullptr, 0, Hb, 2048, dec_ff_b1 + l * DFF_SZ, nullptr, 0, 1);
        gemm(Hb, 2048, Wff2_d + (size_t)l * WFF, 2048, MD, 512, 2048,
             A_dec, 512, nullptr, 0, dec_ff_b2 + l * D_MODEL, A_dec, 512, 0);
    }

    // ---------------- final projection ----------------
    {
        int total = MD * V_SZ;
        hipLaunchKernelGGL(logits_kernel, dim3((total + 255) / 256), dim3(256), 0, stream,
                           A_dec, ll_w, ll_b, (float*)d_out, MD);
    }
    (void)in_sizes; (void)n_in; (void)out_size; (void)ws_size;
}